// Round 4
// baseline (262.824 us; speedup 1.0000x reference)
//
#include <hip/hip_runtime.h>
#include <hip/hip_bf16.h>
#include <stdint.h>

#define B_  2
#define S_  4096
#define D_  768
#define H_  12
#define DH_ 64
#define BS_ (B_*S_)   // 8192

typedef __bf16 bf16x8 __attribute__((ext_vector_type(8)));
typedef short  svec8  __attribute__((ext_vector_type(8)));
typedef float  fvec4  __attribute__((ext_vector_type(4)));
typedef int    ivec4  __attribute__((ext_vector_type(4)));
typedef unsigned short ushort_t;

__device__ __forceinline__ ushort_t f2bf(float f){
    unsigned u = __builtin_bit_cast(unsigned, f);
    unsigned r = (u + 0x7fffu + ((u >> 16) & 1u)) >> 16;
    return (ushort_t)r;
}

__device__ __forceinline__ unsigned cvt_pk_bf16(float lo, float hi){
    unsigned r;
    asm("v_cvt_pk_bf16_f32 %0, %1, %2" : "=v"(r) : "v"(lo), "v"(hi));
    return r;   // low16 = bf16(lo), high16 = bf16(hi)
}

__device__ __forceinline__ fvec4 mfma16(svec8 a, svec8 b, fvec4 c){
    return __builtin_amdgcn_mfma_f32_16x16x32_bf16(
        __builtin_bit_cast(bf16x8, a), __builtin_bit_cast(bf16x8, b), c, 0, 0, 0);
}

// ---------------- fused QKV projection (R12) ----------------
// R12: grid (64,12,3) -> (64,12); one block computes Q,K,V for its 128 rows x head.
// Rationale: qkv was ~115 us (half the pipeline) and L3-BW bound: X (25 MB fp32)
// was read 36x = 905 MB; fused -> 12x = 300 MB, and X staging/f2bf VALU drops 3x.
// acc[3][2][4] = 96 VGPR; LDS 42 KB -> 3 blocks/CU = exactly the 768-block grid
// resident at once (uniform durations, no tail). launch_bounds(256,3) caps ~170 VGPR.
__global__ __launch_bounds__(256, 3) void qkv_proj(
    const float* __restrict__ X,
    const float* __restrict__ Wq, const float* __restrict__ Wk, const float* __restrict__ Wv,
    ushort_t* __restrict__ Qb, ushort_t* __restrict__ Kb, ushort_t* __restrict__ Vg)
{
    const int m0 = blockIdx.x * 128;
    const int h  = blockIdx.y;
    const float* Whs[3] = { Wq + (size_t)h * (D_ * DH_),
                            Wk + (size_t)h * (D_ * DH_),
                            Wv + (size_t)h * (D_ * DH_) };

    __shared__ ushort_t smem[128 * 72 + 3 * 64 * 64];   // 18432 + 24576 B = 42 KB
    ushort_t* Xs  = smem;
    ushort_t* Wts = smem + 128 * 72;
    ushort_t* XsT = smem;              // 64 x 136 overlay, used after K-loop

    const int tid  = threadIdx.x;
    const int w    = tid >> 6;
    const int lane = tid & 63;
    const int quad = lane >> 4;
    const int l15  = lane & 15;

    fvec4 acc[3][2][4];
    #pragma unroll
    for (int wt = 0; wt < 3; wt++)
        #pragma unroll
        for (int i = 0; i < 2; i++)
            #pragma unroll
            for (int j = 0; j < 4; j++) acc[wt][i][j] = (fvec4){0.f, 0.f, 0.f, 0.f};

    for (int k0 = 0; k0 < D_; k0 += 64) {
        // stage X tile once (shared by all three projections)
        #pragma unroll
        for (int i = 0; i < 4; i++) {
            int v = tid + 256 * i;
            int r = v >> 3, c = (v & 7) * 8;
            const float* src = X + (size_t)(m0 + r) * D_ + k0 + c;
            float4 d0 = *(const float4*)(src);
            float4 d1 = *(const float4*)(src + 4);
            svec8 pk;
            pk[0] = (short)f2bf(d0.x); pk[1] = (short)f2bf(d0.y);
            pk[2] = (short)f2bf(d0.z); pk[3] = (short)f2bf(d0.w);
            pk[4] = (short)f2bf(d1.x); pk[5] = (short)f2bf(d1.y);
            pk[6] = (short)f2bf(d1.z); pk[7] = (short)f2bf(d1.w);
            *(svec8*)(Xs + r * 72 + c) = pk;
        }
        // stage all three W panels (swizzled column-major packs)
        #pragma unroll
        for (int wt = 0; wt < 3; wt++)
            #pragma unroll
            for (int i = 0; i < 4; i++) {
                int v = tid + 256 * i;
                int k = v >> 4, t = v & 15;
                float4 d = *(const float4*)(Whs[wt] + (size_t)(k0 + k) * DH_ + t * 4);
                #pragma unroll
                for (int j = 0; j < 4; j++) {
                    int n = t * 4 + j;
                    int addr = wt * 4096 + n * 64 + ((((k >> 3) ^ (t & 7))) << 3) + (k & 7);
                    Wts[addr] = f2bf(j == 0 ? d.x : j == 1 ? d.y : j == 2 ? d.z : d.w);
                }
            }
        __syncthreads();

        #pragma unroll
        for (int ks = 0; ks < 2; ks++) {
            svec8 a0 = *(const svec8*)(Xs + (32 * w + l15) * 72 + ks * 32 + quad * 8);
            svec8 a1 = *(const svec8*)(Xs + (32 * w + 16 + l15) * 72 + ks * 32 + quad * 8);
            #pragma unroll
            for (int wt = 0; wt < 3; wt++)
                #pragma unroll
                for (int ns = 0; ns < 4; ns++) {
                    int n = ns * 16 + l15;
                    int swz = (ks * 4 + quad) ^ ((n >> 2) & 7);
                    svec8 b = *(const svec8*)(Wts + wt * 4096 + n * 64 + swz * 8);
                    acc[wt][0][ns] = mfma16(a0, b, acc[wt][0][ns]);
                    acc[wt][1][ns] = mfma16(a1, b, acc[wt][1][ns]);
                }
        }
        __syncthreads();
    }

    // epilogue: Q (pre-scaled to log2 domain) and K direct stores
    const float qs = 0.18033688011112042f;   // 1/8 * log2(e)
    #pragma unroll
    for (int ms = 0; ms < 2; ms++)
        #pragma unroll
        for (int ns = 0; ns < 4; ns++)
            #pragma unroll
            for (int r = 0; r < 4; r++) {
                int row = m0 + 32 * w + ms * 16 + quad * 4 + r;
                int col = h * DH_ + ns * 16 + l15;
                Qb[(size_t)row * D_ + col] = f2bf(acc[0][ms][ns][r] * qs);
                Kb[(size_t)row * D_ + col] = f2bf(acc[1][ms][ns][r]);
            }
    // V: transpose through LDS (Xs region is free after the loop's final barrier)
    #pragma unroll
    for (int ms = 0; ms < 2; ms++)
        #pragma unroll
        for (int ns = 0; ns < 4; ns++)
            #pragma unroll
            for (int r = 0; r < 4; r++) {
                int sl = 32 * w + ms * 16 + quad * 4 + r;
                int e  = ns * 16 + l15;
                XsT[e * 136 + sl] = f2bf(acc[2][ms][ns][r]);
            }
    __syncthreads();
    #pragma unroll
    for (int i = 0; i < 4; i++) {
        int v = tid + 256 * i;
        int e = v >> 4, s0 = (v & 15) * 8;
        svec8 d = *(const svec8*)(XsT + e * 136 + s0);
        *(svec8*)(Vg + (size_t)(h * DH_ + e) * BS_ + m0 + s0) = d;
    }
}

// ---------------- causal flash attention (R12: VALU-trimmed softmax) ----------------
// Structure from R11 (flat de-aliased grid, swapped QK^T, in-register P, spill-free
// at 48 VGPR). SQ_LDS_BANK_CONFLICT 1.28e7 is the b128 LDS-BW floor (64 lanes x 16B
// = 1 KiB/inst vs 128 B/cy) -- not fixable by swizzle, so R12 attacks the VALU side:
//  - P packing via v_cvt_pk_bf16_f32 (8 ops vs ~32 shift/inserts)
//  - skip-rescale: if !__any(mx > m_i) the rescale is exactly x1.0 -> skip the
//    16 muls + 4 bpermutes + exp2 (taken on ~half the tiles; bit-exact numerics)
//  - max3-friendly fmax chains (15 -> 9 ops), tree-summed denominator (kills a
//    16-deep serial add chain), strength-reduced prefetch pointers.
__global__ __launch_bounds__(256, 5) void attn(
    const ushort_t* __restrict__ Qb, const ushort_t* __restrict__ Kb,
    const ushort_t* __restrict__ Vg, float* __restrict__ Out)
{
    const int fid = blockIdx.x;                        // 0..1535 flat
    const int qt  = (S_ / 64 - 1) - fid / (H_ * B_);   // long tiles first, de-aliased
    const int r24 = fid % (H_ * B_);
    const int h   = r24 % H_;
    const int b   = r24 / H_;
    const int q0 = qt * 64;

    const int tid  = threadIdx.x;
    const int w    = tid >> 6;
    const int lane = tid & 63;
    const int quad = lane >> 4;
    const int l15  = lane & 15;

    __shared__ ushort_t Ks[64 * 72];       // K tile, ROW-PERMUTED: LDS row m = key pi(m)
    __shared__ ushort_t Vt[64 * 72];       // V^T tile [e][key]

    const size_t hb = (size_t)b * S_ * D_ + (size_t)h * DH_;
    const ushort_t* Vh = Vg + (size_t)h * DH_ * BS_ + (size_t)b * S_;

    const int sr = tid >> 3;          // staging row 0..31 (+32)
    const int sc = (tid & 7) * 8;
    // pinv(k): LDS row where key k lives.  m4=k5, m3=k4, m2=k3, m5=k2, m1m0=k1k0
    const int pr0 = (((sr      >> 2) & 1) << 5) | (((sr      >> 5) & 1) << 4) |
                    (((sr      >> 4) & 1) << 3) | (((sr      >> 3) & 1) << 2) | (sr & 3);
    const int sr1 = sr + 32;
    const int pr1 = (((sr1 >> 2) & 1) << 5) | (((sr1 >> 5) & 1) << 4) |
                    (((sr1 >> 4) & 1) << 3) | (((sr1 >> 3) & 1) << 2) | (sr1 & 3);

    // Q fragments (pre-scaled to log2 domain in qkv_proj); B-operand, same layout
    svec8 aq[2];
    {
        const ushort_t* qrow = Qb + hb + (size_t)(q0 + 16 * w + l15) * D_;
        aq[0] = *(const svec8*)(qrow + quad * 8);
        aq[1] = *(const svec8*)(qrow + 32 + quad * 8);
    }

    float m_i = -INFINITY;
    float ls  = 0.f;                  // per-lane partial denominator (row q = l15)
    fvec4 acc[4];
    #pragma unroll
    for (int n = 0; n < 4; n++) acc[n] = (fvec4){0.f, 0.f, 0.f, 0.f};

    // strength-reduced prefetch pointers (advance per tile)
    const ushort_t* kp = Kb + hb + (size_t)sr * D_ + sc;
    const ushort_t* vp = Vh + (size_t)sr * BS_ + sc;

    // prologue: stage tile 0
    svec8 kd[2], vd[2];
    kd[0] = *(const svec8*)(kp);
    kd[1] = *(const svec8*)(kp + (size_t)32 * D_);
    vd[0] = *(const svec8*)(vp);
    vd[1] = *(const svec8*)(vp + (size_t)32 * BS_);
    kp += (size_t)64 * D_;
    vp += 64;
    *(svec8*)(Ks + pr0 * 72 + sc) = kd[0];
    *(svec8*)(Ks + pr1 * 72 + sc) = kd[1];
    *(svec8*)(Vt + sr  * 72 + sc) = vd[0];
    *(svec8*)(Vt + sr1 * 72 + sc) = vd[1];

    for (int kt = 0; kt <= qt; ++kt) {
        __syncthreads();   // staged tile kt visible to all waves

        // prefetch next tile into registers (in flight across the compute phase)
        if (kt < qt) {
            kd[0] = *(const svec8*)(kp);
            kd[1] = *(const svec8*)(kp + (size_t)32 * D_);
            vd[0] = *(const svec8*)(vp);
            vd[1] = *(const svec8*)(vp + (size_t)32 * BS_);
            kp += (size_t)64 * D_;
            vp += 64;
        }

        // S^T = K_perm Q^T  (log2 domain via pre-scaled Q); lane holds row q = l15
        fvec4 st[4];
        #pragma unroll
        for (int n = 0; n < 4; n++) st[n] = (fvec4){0.f, 0.f, 0.f, 0.f};
        #pragma unroll
        for (int ks = 0; ks < 2; ks++)
            #pragma unroll
            for (int n = 0; n < 4; n++) {
                svec8 ka = *(const svec8*)(Ks + (n * 16 + l15) * 72 + ks * 32 + quad * 8);
                st[n] = mfma16(ka, aq[ks], st[n]);
            }

        // causal mask on the diagonal tile: key pi(m) vs q row
        if (kt == qt) {
            #pragma unroll
            for (int n = 0; n < 4; n++)
                #pragma unroll
                for (int r = 0; r < 4; r++) {
                    int key = (n & 1) * 32 + quad * 8 + (n >> 1) * 4 + r;
                    int row = 16 * w + l15;
                    if (key > row) st[n][r] = -INFINITY;
                }
        }

        // per-row max: two max3-friendly chains, then 2-step butterfly across quads
        float mxa = fmaxf(fmaxf(st[0][0], st[0][1]), st[0][2]);
        mxa = fmaxf(fmaxf(mxa, st[0][3]), st[1][0]);
        mxa = fmaxf(fmaxf(mxa, st[1][1]), st[1][2]);
        mxa = fmaxf(mxa, st[1][3]);
        float mxb = fmaxf(fmaxf(st[2][0], st[2][1]), st[2][2]);
        mxb = fmaxf(fmaxf(mxb, st[2][3]), st[3][0]);
        mxb = fmaxf(fmaxf(mxb, st[3][1]), st[3][2]);
        mxb = fmaxf(mxb, st[3][3]);
        float mx = fmaxf(mxa, mxb);
        mx = fmaxf(mx, __shfl_xor(mx, 16));
        mx = fmaxf(mx, __shfl_xor(mx, 32));

        // skip-rescale: alpha == 1.0 for every row unless some row's max grew.
        // (Exact: rows that didn't grow get alpha = exp2(0) = 1 in the taken branch.)
        if (__any(mx > m_i)) {
            float mn = fmaxf(m_i, mx);
            float alpha = exp2f(m_i - mn);
            m_i = mn;
            ls *= alpha;
            float ar[4];
            #pragma unroll
            for (int r = 0; r < 4; r++)
                ar[r] = __shfl(alpha, quad * 16 + quad * 4 + r);
            #pragma unroll
            for (int n = 0; n < 4; n++)
                #pragma unroll
                for (int r = 0; r < 4; r++) acc[n][r] *= ar[r];
        }

        // p = exp2(st - m_i); pack pairs with v_cvt_pk_bf16_f32; tree-sum denominator
        ivec4 ai0, ai1;
        float psum[4];
        #pragma unroll
        for (int n = 0; n < 4; n++) {
            float p0 = exp2f(st[n][0] - m_i);
            float p1 = exp2f(st[n][1] - m_i);
            float p2 = exp2f(st[n][2] - m_i);
            float p3 = exp2f(st[n][3] - m_i);
            psum[n] = (p0 + p1) + (p2 + p3);
            unsigned d0 = cvt_pk_bf16(p0, p1);
            unsigned d1 = cvt_pk_bf16(p2, p3);
            if (n == 0)      { ai0[0] = (int)d0; ai0[1] = (int)d1; }
            else if (n == 1) { ai1[0] = (int)d0; ai1[1] = (int)d1; }
            else if (n == 2) { ai0[2] = (int)d0; ai0[3] = (int)d1; }
            else             { ai1[2] = (int)d0; ai1[3] = (int)d1; }
        }
        ls += (psum[0] + psum[2]) + (psum[1] + psum[3]);
        svec8 ap0 = __builtin_bit_cast(svec8, ai0);
        svec8 ap1 = __builtin_bit_cast(svec8, ai1);

        // O += P V   (A = in-register P fragment, B = V^T from LDS)
        #pragma unroll
        for (int ks = 0; ks < 2; ks++) {
            svec8 ap = ks ? ap1 : ap0;
            #pragma unroll
            for (int n = 0; n < 4; n++) {
                svec8 bv = *(const svec8*)(Vt + (n * 16 + l15) * 72 + ks * 32 + quad * 8);
                acc[n] = mfma16(ap, bv, acc[n]);
            }
        }

        __syncthreads();   // all waves done reading tile kt

        if (kt < qt) {
            *(svec8*)(Ks + pr0 * 72 + sc) = kd[0];
            *(svec8*)(Ks + pr1 * 72 + sc) = kd[1];
            *(svec8*)(Vt + sr  * 72 + sc) = vd[0];
            *(svec8*)(Vt + sr1 * 72 + sc) = vd[1];
        }
    }

    // epilogue: full denominator for row l15 (2 shuffles), then fetch per-acc-row
    float lsum = ls;
    lsum += __shfl_xor(lsum, 16);
    lsum += __shfl_xor(lsum, 32);
    float li[4];
    #pragma unroll
    for (int r = 0; r < 4; r++)
        li[r] = __shfl(lsum, quad * 16 + quad * 4 + r);
    #pragma unroll
    for (int n = 0; n < 4; n++)
        #pragma unroll
        for (int r = 0; r < 4; r++) {
            int row = q0 + 16 * w + quad * 4 + r;
            int col = h * DH_ + n * 16 + l15;
            Out[((size_t)b * S_ + row) * D_ + col] = acc[n][r] / li[r];
        }
}

extern "C" void kernel_launch(void* const* d_in, const int* in_sizes, int n_in,
                              void* d_out, int out_size, void* d_ws, size_t ws_size,
                              hipStream_t stream)
{
    const float* X  = (const float*)d_in[0];
    const float* Wq = (const float*)d_in[1];
    const float* Wk = (const float*)d_in[2];
    const float* Wv = (const float*)d_in[3];

    ushort_t* Qb = (ushort_t*)d_ws;                      // 8192*768 bf16 (pre-scaled)
    ushort_t* Kb = Qb + (size_t)BS_ * D_;                // 8192*768 bf16
    ushort_t* Vg = Kb + (size_t)BS_ * D_;                // [768][8192] bf16 transposed
    float* Out = (float*)d_out;

    qkv_proj<<<dim3(64, H_), dim3(256), 0, stream>>>(X, Wq, Wk, Wv, Qb, Kb, Vg);
    attn<<<dim3((S_ / 64) * H_ * B_), dim3(256), 0, stream>>>(Qb, Kb, Vg, Out);
}

// Round 5
// 246.725 us; speedup vs baseline: 1.0652x; 1.0652x over previous
//
#include <hip/hip_runtime.h>
#include <hip/hip_bf16.h>
#include <stdint.h>

#define B_  2
#define S_  4096
#define D_  768
#define H_  12
#define DH_ 64
#define BS_ (B_*S_)   // 8192

typedef __bf16 bf16x8 __attribute__((ext_vector_type(8)));
typedef short  svec8  __attribute__((ext_vector_type(8)));
typedef float  fvec4  __attribute__((ext_vector_type(4)));
typedef int    ivec4  __attribute__((ext_vector_type(4)));
typedef unsigned short ushort_t;

// native RNE float->bf16 (compiler emits v_cvt_pk_bf16_f32 for pairs; bit-identical
// to the old manual round-nearest-even bit-twiddle on non-NaN inputs)
__device__ __forceinline__ ushort_t bfc(float f){
    return __builtin_bit_cast(ushort_t, (__bf16)f);
}

__device__ __forceinline__ unsigned cvt_pk_bf16(float lo, float hi){
    unsigned r;
    asm("v_cvt_pk_bf16_f32 %0, %1, %2" : "=v"(r) : "v"(lo), "v"(hi));
    return r;   // low16 = bf16(lo), high16 = bf16(hi)
}

__device__ __forceinline__ fvec4 mfma16(svec8 a, svec8 b, fvec4 c){
    return __builtin_amdgcn_mfma_f32_16x16x32_bf16(
        __builtin_bit_cast(bf16x8, a), __builtin_bit_cast(bf16x8, b), c, 0, 0, 0);
}

// ---------------- prep: one-shot convert + swizzle (R13) ----------------
// R12 post-mortem: fused qkv was ~151 us, bound by per-k-tile staging VALU
// (48 f2bf + 48 scattered ds_write_b16 per thread for W). Fix: do conversions ONCE.
//  - blocks [0,3072):  X fp32 -> bf16 Xb [8192][768]   (read 25 MB, write 12.6 MB)
//  - blocks [3072,3504): W fp32 -> bf16 PRE-SWIZZLED panels Wsz[h][kt][wt][4096]
//    with addr = n*64 + (((k>>3)^((n>>2)&7))<<3) + (k&7) -- exactly the LDS layout
//    qkv's MFMA B-reads expect, so qkv staging becomes a linear b128 copy.
__global__ __launch_bounds__(256) void prep(
    const float* __restrict__ X,
    const float* __restrict__ Wq, const float* __restrict__ Wk, const float* __restrict__ Wv,
    ushort_t* __restrict__ Xb, ushort_t* __restrict__ Wsz)
{
    const int bid = blockIdx.x;
    if (bid < 3072) {
        size_t idx = ((size_t)bid * 256 + threadIdx.x) * 8;
        float4 d0 = *(const float4*)(X + idx);
        float4 d1 = *(const float4*)(X + idx + 4);
        bf16x8 pk;
        pk[0] = (__bf16)d0.x; pk[1] = (__bf16)d0.y;
        pk[2] = (__bf16)d0.z; pk[3] = (__bf16)d0.w;
        pk[4] = (__bf16)d1.x; pk[5] = (__bf16)d1.y;
        pk[6] = (__bf16)d1.z; pk[7] = (__bf16)d1.w;
        *(svec8*)(Xb + idx) = __builtin_bit_cast(svec8, pk);
    } else {
        const int v  = bid - 3072;        // 0..431
        const int wt = v % 3;
        const int hk = v / 3;             // h*12 + kt
        const int h  = hk / 12, kt = hk % 12;
        const float* W  = (wt == 0) ? Wq : (wt == 1) ? Wk : Wv;
        const float* Wh = W + (size_t)h * (D_ * DH_) + (size_t)kt * 64 * DH_;
        ushort_t* dst = Wsz + (size_t)(hk * 3 + wt) * 4096;
        #pragma unroll
        for (int i = 0; i < 16; i++) {
            int idx = threadIdx.x * 16 + i;          // 0..4095
            int k = idx >> 6, n = idx & 63;
            float val = Wh[k * DH_ + n];
            int addr = n * 64 + ((((k >> 3) ^ ((n >> 2) & 7))) << 3) + (k & 7);
            dst[addr] = bfc(val);
        }
    }
}

// ---------------- fused QKV projection (R13: copy-only staging) ----------------
// Grid (64,12): one block computes Q,K,V for its 128 rows x head (X read 12x not
// 36x). Staging is now pure b128 copies from pre-converted Xb / pre-swizzled Wsz:
// per k-tile per thread 4+6 load/store pairs vs R12's ~300 VALU ops + 52 scattered
// writes. LDS 42 KB -> 3 blocks/CU (= the 768-block grid fully resident, no tail).
__global__ __launch_bounds__(256, 3) void qkv_proj(
    const ushort_t* __restrict__ Xb, const ushort_t* __restrict__ Wsz,
    ushort_t* __restrict__ Qb, ushort_t* __restrict__ Kb, ushort_t* __restrict__ Vg)
{
    const int m0 = blockIdx.x * 128;
    const int h  = blockIdx.y;

    __shared__ ushort_t smem[128 * 72 + 3 * 4096];   // 18432 + 24576 B = 42 KB
    ushort_t* Xs  = smem;
    ushort_t* Wts = smem + 128 * 72;
    ushort_t* XsT = smem;              // 64 x 136 overlay, used after K-loop

    const int tid  = threadIdx.x;
    const int w    = tid >> 6;
    const int lane = tid & 63;
    const int quad = lane >> 4;
    const int l15  = lane & 15;

    fvec4 acc[3][2][4];
    #pragma unroll
    for (int wt = 0; wt < 3; wt++)
        #pragma unroll
        for (int i = 0; i < 2; i++)
            #pragma unroll
            for (int j = 0; j < 4; j++) acc[wt][i][j] = (fvec4){0.f, 0.f, 0.f, 0.f};

    for (int kt = 0; kt < 12; kt++) {
        const int k0 = kt * 64;
        // stage X tile (pure copy, shared by all three projections)
        #pragma unroll
        for (int i = 0; i < 4; i++) {
            int v = tid + 256 * i;
            int r = v >> 3, c = (v & 7) * 8;
            *(svec8*)(Xs + r * 72 + c) =
                *(const svec8*)(Xb + (size_t)(m0 + r) * D_ + k0 + c);
        }
        // stage all three W panels (linear copy of pre-swizzled data)
        const ushort_t* wsrc = Wsz + (size_t)(h * 12 + kt) * 3 * 4096;
        #pragma unroll
        for (int j = 0; j < 6; j++) {
            int lin = (tid + 256 * j) * 8;
            *(svec8*)(Wts + lin) = *(const svec8*)(wsrc + lin);
        }
        __syncthreads();

        #pragma unroll
        for (int ks = 0; ks < 2; ks++) {
            svec8 a0 = *(const svec8*)(Xs + (32 * w + l15) * 72 + ks * 32 + quad * 8);
            svec8 a1 = *(const svec8*)(Xs + (32 * w + 16 + l15) * 72 + ks * 32 + quad * 8);
            #pragma unroll
            for (int wt = 0; wt < 3; wt++)
                #pragma unroll
                for (int ns = 0; ns < 4; ns++) {
                    int n = ns * 16 + l15;
                    int swz = (ks * 4 + quad) ^ ((n >> 2) & 7);
                    svec8 b = *(const svec8*)(Wts + wt * 4096 + n * 64 + swz * 8);
                    acc[wt][0][ns] = mfma16(a0, b, acc[wt][0][ns]);
                    acc[wt][1][ns] = mfma16(a1, b, acc[wt][1][ns]);
                }
        }
        __syncthreads();
    }

    // epilogue: Q (pre-scaled to log2 domain) and K direct stores
    const float qs = 0.18033688011112042f;   // 1/8 * log2(e)
    #pragma unroll
    for (int ms = 0; ms < 2; ms++)
        #pragma unroll
        for (int ns = 0; ns < 4; ns++)
            #pragma unroll
            for (int r = 0; r < 4; r++) {
                int row = m0 + 32 * w + ms * 16 + quad * 4 + r;
                int col = h * DH_ + ns * 16 + l15;
                Qb[(size_t)row * D_ + col] = bfc(acc[0][ms][ns][r] * qs);
                Kb[(size_t)row * D_ + col] = bfc(acc[1][ms][ns][r]);
            }
    // V: transpose through LDS (Xs region is free after the loop's final barrier)
    #pragma unroll
    for (int ms = 0; ms < 2; ms++)
        #pragma unroll
        for (int ns = 0; ns < 4; ns++)
            #pragma unroll
            for (int r = 0; r < 4; r++) {
                int sl = 32 * w + ms * 16 + quad * 4 + r;
                int e  = ns * 16 + l15;
                XsT[e * 136 + sl] = bfc(acc[2][ms][ns][r]);
            }
    __syncthreads();
    #pragma unroll
    for (int i = 0; i < 4; i++) {
        int v = tid + 256 * i;
        int e = v >> 4, s0 = (v & 15) * 8;
        svec8 d = *(const svec8*)(XsT + e * 136 + s0);
        *(svec8*)(Vg + (size_t)(h * DH_ + e) * BS_ + m0 + s0) = d;
    }
}

// ---------------- causal flash attention (R12 kernel, unchanged) ----------------
// Flat de-aliased grid, swapped QK^T, in-register P, spill-free at 48 VGPR,
// skip-rescale + cvt_pk packing. 111.7 us, MfmaUtil 20 / VALUBusy 66.
__global__ __launch_bounds__(256, 5) void attn(
    const ushort_t* __restrict__ Qb, const ushort_t* __restrict__ Kb,
    const ushort_t* __restrict__ Vg, float* __restrict__ Out)
{
    const int fid = blockIdx.x;                        // 0..1535 flat
    const int qt  = (S_ / 64 - 1) - fid / (H_ * B_);   // long tiles first, de-aliased
    const int r24 = fid % (H_ * B_);
    const int h   = r24 % H_;
    const int b   = r24 / H_;
    const int q0 = qt * 64;

    const int tid  = threadIdx.x;
    const int w    = tid >> 6;
    const int lane = tid & 63;
    const int quad = lane >> 4;
    const int l15  = lane & 15;

    __shared__ ushort_t Ks[64 * 72];       // K tile, ROW-PERMUTED: LDS row m = key pi(m)
    __shared__ ushort_t Vt[64 * 72];       // V^T tile [e][key]

    const size_t hb = (size_t)b * S_ * D_ + (size_t)h * DH_;
    const ushort_t* Vh = Vg + (size_t)h * DH_ * BS_ + (size_t)b * S_;

    const int sr = tid >> 3;          // staging row 0..31 (+32)
    const int sc = (tid & 7) * 8;
    // pinv(k): LDS row where key k lives.  m4=k5, m3=k4, m2=k3, m5=k2, m1m0=k1k0
    const int pr0 = (((sr      >> 2) & 1) << 5) | (((sr      >> 5) & 1) << 4) |
                    (((sr      >> 4) & 1) << 3) | (((sr      >> 3) & 1) << 2) | (sr & 3);
    const int sr1 = sr + 32;
    const int pr1 = (((sr1 >> 2) & 1) << 5) | (((sr1 >> 5) & 1) << 4) |
                    (((sr1 >> 4) & 1) << 3) | (((sr1 >> 3) & 1) << 2) | (sr1 & 3);

    // Q fragments (pre-scaled to log2 domain in qkv_proj); B-operand, same layout
    svec8 aq[2];
    {
        const ushort_t* qrow = Qb + hb + (size_t)(q0 + 16 * w + l15) * D_;
        aq[0] = *(const svec8*)(qrow + quad * 8);
        aq[1] = *(const svec8*)(qrow + 32 + quad * 8);
    }

    float m_i = -INFINITY;
    float ls  = 0.f;                  // per-lane partial denominator (row q = l15)
    fvec4 acc[4];
    #pragma unroll
    for (int n = 0; n < 4; n++) acc[n] = (fvec4){0.f, 0.f, 0.f, 0.f};

    // strength-reduced prefetch pointers (advance per tile)
    const ushort_t* kp = Kb + hb + (size_t)sr * D_ + sc;
    const ushort_t* vp = Vh + (size_t)sr * BS_ + sc;

    // prologue: stage tile 0
    svec8 kd[2], vd[2];
    kd[0] = *(const svec8*)(kp);
    kd[1] = *(const svec8*)(kp + (size_t)32 * D_);
    vd[0] = *(const svec8*)(vp);
    vd[1] = *(const svec8*)(vp + (size_t)32 * BS_);
    kp += (size_t)64 * D_;
    vp += 64;
    *(svec8*)(Ks + pr0 * 72 + sc) = kd[0];
    *(svec8*)(Ks + pr1 * 72 + sc) = kd[1];
    *(svec8*)(Vt + sr  * 72 + sc) = vd[0];
    *(svec8*)(Vt + sr1 * 72 + sc) = vd[1];

    for (int kt = 0; kt <= qt; ++kt) {
        __syncthreads();   // staged tile kt visible to all waves

        // prefetch next tile into registers (in flight across the compute phase)
        if (kt < qt) {
            kd[0] = *(const svec8*)(kp);
            kd[1] = *(const svec8*)(kp + (size_t)32 * D_);
            vd[0] = *(const svec8*)(vp);
            vd[1] = *(const svec8*)(vp + (size_t)32 * BS_);
            kp += (size_t)64 * D_;
            vp += 64;
        }

        // S^T = K_perm Q^T  (log2 domain via pre-scaled Q); lane holds row q = l15
        fvec4 st[4];
        #pragma unroll
        for (int n = 0; n < 4; n++) st[n] = (fvec4){0.f, 0.f, 0.f, 0.f};
        #pragma unroll
        for (int ks = 0; ks < 2; ks++)
            #pragma unroll
            for (int n = 0; n < 4; n++) {
                svec8 ka = *(const svec8*)(Ks + (n * 16 + l15) * 72 + ks * 32 + quad * 8);
                st[n] = mfma16(ka, aq[ks], st[n]);
            }

        // causal mask on the diagonal tile: key pi(m) vs q row
        if (kt == qt) {
            #pragma unroll
            for (int n = 0; n < 4; n++)
                #pragma unroll
                for (int r = 0; r < 4; r++) {
                    int key = (n & 1) * 32 + quad * 8 + (n >> 1) * 4 + r;
                    int row = 16 * w + l15;
                    if (key > row) st[n][r] = -INFINITY;
                }
        }

        // per-row max: two max3-friendly chains, then 2-step butterfly across quads
        float mxa = fmaxf(fmaxf(st[0][0], st[0][1]), st[0][2]);
        mxa = fmaxf(fmaxf(mxa, st[0][3]), st[1][0]);
        mxa = fmaxf(fmaxf(mxa, st[1][1]), st[1][2]);
        mxa = fmaxf(mxa, st[1][3]);
        float mxb = fmaxf(fmaxf(st[2][0], st[2][1]), st[2][2]);
        mxb = fmaxf(fmaxf(mxb, st[2][3]), st[3][0]);
        mxb = fmaxf(fmaxf(mxb, st[3][1]), st[3][2]);
        mxb = fmaxf(mxb, st[3][3]);
        float mx = fmaxf(mxa, mxb);
        mx = fmaxf(mx, __shfl_xor(mx, 16));
        mx = fmaxf(mx, __shfl_xor(mx, 32));

        // skip-rescale: alpha == 1.0 for every row unless some row's max grew.
        if (__any(mx > m_i)) {
            float mn = fmaxf(m_i, mx);
            float alpha = exp2f(m_i - mn);
            m_i = mn;
            ls *= alpha;
            float ar[4];
            #pragma unroll
            for (int r = 0; r < 4; r++)
                ar[r] = __shfl(alpha, quad * 16 + quad * 4 + r);
            #pragma unroll
            for (int n = 0; n < 4; n++)
                #pragma unroll
                for (int r = 0; r < 4; r++) acc[n][r] *= ar[r];
        }

        // p = exp2(st - m_i); pack pairs with v_cvt_pk_bf16_f32; tree-sum denominator
        ivec4 ai0, ai1;
        float psum[4];
        #pragma unroll
        for (int n = 0; n < 4; n++) {
            float p0 = exp2f(st[n][0] - m_i);
            float p1 = exp2f(st[n][1] - m_i);
            float p2 = exp2f(st[n][2] - m_i);
            float p3 = exp2f(st[n][3] - m_i);
            psum[n] = (p0 + p1) + (p2 + p3);
            unsigned d0 = cvt_pk_bf16(p0, p1);
            unsigned d1 = cvt_pk_bf16(p2, p3);
            if (n == 0)      { ai0[0] = (int)d0; ai0[1] = (int)d1; }
            else if (n == 1) { ai1[0] = (int)d0; ai1[1] = (int)d1; }
            else if (n == 2) { ai0[2] = (int)d0; ai0[3] = (int)d1; }
            else             { ai1[2] = (int)d0; ai1[3] = (int)d1; }
        }
        ls += (psum[0] + psum[2]) + (psum[1] + psum[3]);
        svec8 ap0 = __builtin_bit_cast(svec8, ai0);
        svec8 ap1 = __builtin_bit_cast(svec8, ai1);

        // O += P V   (A = in-register P fragment, B = V^T from LDS)
        #pragma unroll
        for (int ks = 0; ks < 2; ks++) {
            svec8 ap = ks ? ap1 : ap0;
            #pragma unroll
            for (int n = 0; n < 4; n++) {
                svec8 bv = *(const svec8*)(Vt + (n * 16 + l15) * 72 + ks * 32 + quad * 8);
                acc[n] = mfma16(ap, bv, acc[n]);
            }
        }

        __syncthreads();   // all waves done reading tile kt

        if (kt < qt) {
            *(svec8*)(Ks + pr0 * 72 + sc) = kd[0];
            *(svec8*)(Ks + pr1 * 72 + sc) = kd[1];
            *(svec8*)(Vt + sr  * 72 + sc) = vd[0];
            *(svec8*)(Vt + sr1 * 72 + sc) = vd[1];
        }
    }

    // epilogue: full denominator for row l15 (2 shuffles), then fetch per-acc-row
    float lsum = ls;
    lsum += __shfl_xor(lsum, 16);
    lsum += __shfl_xor(lsum, 32);
    float li[4];
    #pragma unroll
    for (int r = 0; r < 4; r++)
        li[r] = __shfl(lsum, quad * 16 + quad * 4 + r);
    #pragma unroll
    for (int n = 0; n < 4; n++)
        #pragma unroll
        for (int r = 0; r < 4; r++) {
            int row = q0 + 16 * w + quad * 4 + r;
            int col = h * DH_ + n * 16 + l15;
            Out[((size_t)b * S_ + row) * D_ + col] = acc[n][r] / li[r];
        }
}

extern "C" void kernel_launch(void* const* d_in, const int* in_sizes, int n_in,
                              void* d_out, int out_size, void* d_ws, size_t ws_size,
                              hipStream_t stream)
{
    const float* X  = (const float*)d_in[0];
    const float* Wq = (const float*)d_in[1];
    const float* Wk = (const float*)d_in[2];
    const float* Wv = (const float*)d_in[3];

    ushort_t* Qb = (ushort_t*)d_ws;                      // 8192*768 bf16 (pre-scaled)
    ushort_t* Kb = Qb + (size_t)BS_ * D_;                // 8192*768 bf16
    ushort_t* Vg = Kb + (size_t)BS_ * D_;                // [768][8192] bf16 transposed

    // scratch inside d_out (25.2 MB fp32 buffer): attn fully overwrites it at the
    // end, and prep/qkv/attn serialize on one stream -> safe.
    ushort_t* Xb  = (ushort_t*)d_out;                    // [8192][768] bf16 (12.6 MB)
    ushort_t* Wsz = Xb + (size_t)BS_ * D_;               // [h][kt][wt][4096] (3.5 MB)
    float* Out = (float*)d_out;

    prep<<<dim3(3072 + 432), dim3(256), 0, stream>>>(X, Wq, Wk, Wv, Xb, Wsz);
    qkv_proj<<<dim3(64, H_), dim3(256), 0, stream>>>(Xb, Wsz, Qb, Kb, Vg);
    attn<<<dim3((S_ / 64) * H_ * B_), dim3(256), 0, stream>>>(Qb, Kb, Vg, Out);
}

// Round 6
// 219.350 us; speedup vs baseline: 1.1982x; 1.1248x over previous
//
#include <hip/hip_runtime.h>
#include <hip/hip_bf16.h>
#include <stdint.h>

#define B_  2
#define S_  4096
#define D_  768
#define H_  12
#define DH_ 64
#define BS_ (B_*S_)   // 8192

typedef __bf16 bf16x8 __attribute__((ext_vector_type(8)));
typedef short  svec8  __attribute__((ext_vector_type(8)));
typedef float  fvec4  __attribute__((ext_vector_type(4)));
typedef int    ivec4  __attribute__((ext_vector_type(4)));
typedef unsigned short ushort_t;

// native RNE float->bf16
__device__ __forceinline__ ushort_t bfc(float f){
    return __builtin_bit_cast(ushort_t, (__bf16)f);
}

__device__ __forceinline__ unsigned cvt_pk_bf16(float lo, float hi){
    unsigned r;
    asm("v_cvt_pk_bf16_f32 %0, %1, %2" : "=v"(r) : "v"(lo), "v"(hi));
    return r;   // low16 = bf16(lo), high16 = bf16(hi)
}

__device__ __forceinline__ fvec4 mfma16(svec8 a, svec8 b, fvec4 c){
    return __builtin_amdgcn_mfma_f32_16x16x32_bf16(
        __builtin_bit_cast(bf16x8, a), __builtin_bit_cast(bf16x8, b), c, 0, 0, 0);
}

// ---------------- prep: one-shot convert + fragment-swizzle (R14) ----------------
//  - blocks [0,3072):  X fp32 -> bf16 Xb [8192][768]
//  - blocks [3072,3504): W fp32 -> bf16 FRAGMENT-LINEAR panels Wsz[h][kt][wt][4096]:
//    element W[k][n] (k,n within 64x64 tile) at
//      (((k>>5)*4 + (n>>4))*64 + (n&15)*4 + ((k>>3)&3))*8 + (k&7)
//    so qkv's MFMA B-read for (ks,ns) is base + (l15*4+quad)*16B -- lane-consecutive,
//    bank-conflict-free, and address math is one shared base + one lane constant.
__global__ __launch_bounds__(256) void prep(
    const float* __restrict__ X,
    const float* __restrict__ Wq, const float* __restrict__ Wk, const float* __restrict__ Wv,
    ushort_t* __restrict__ Xb, ushort_t* __restrict__ Wsz)
{
    const int bid = blockIdx.x;
    if (bid < 3072) {
        size_t idx = ((size_t)bid * 256 + threadIdx.x) * 8;
        float4 d0 = *(const float4*)(X + idx);
        float4 d1 = *(const float4*)(X + idx + 4);
        bf16x8 pk;
        pk[0] = (__bf16)d0.x; pk[1] = (__bf16)d0.y;
        pk[2] = (__bf16)d0.z; pk[3] = (__bf16)d0.w;
        pk[4] = (__bf16)d1.x; pk[5] = (__bf16)d1.y;
        pk[6] = (__bf16)d1.z; pk[7] = (__bf16)d1.w;
        *(svec8*)(Xb + idx) = __builtin_bit_cast(svec8, pk);
    } else {
        const int v  = bid - 3072;        // 0..431
        const int wt = v % 3;
        const int hk = v / 3;             // h*12 + kt
        const int h  = hk / 12, kt = hk % 12;
        const float* W  = (wt == 0) ? Wq : (wt == 1) ? Wk : Wv;
        const float* Wh = W + (size_t)h * (D_ * DH_) + (size_t)kt * 64 * DH_;
        ushort_t* dst = Wsz + (size_t)(hk * 3 + wt) * 4096;
        #pragma unroll
        for (int i = 0; i < 16; i++) {
            int idx = threadIdx.x * 16 + i;          // 0..4095
            int k = idx >> 6, n = idx & 63;
            float val = Wh[k * DH_ + n];
            int addr = (((k >> 5) * 4 + (n >> 4)) * 64 + (n & 15) * 4 + ((k >> 3) & 3)) * 8
                     + (k & 7);
            dst[addr] = bfc(val);
        }
    }
}

// ---------------- fused QKV projection (R14: pipelined + conflict-free) -------------
// R13 post-mortem: copy-staging only saved ~18 us -> qkv is latency-bound (no overlap
// in the k-loop) plus 2x-conflicted B-reads (16 lanes per 4-bank group under the old
// swizzle). R14:
//  - X register prefetch: load tile kt+1 during kt's MFMA phase (attn-style), so
//    L3/HBM latency hides under compute. W stays synchronous (L2-hot: 64 blocks/head
//    reuse a 3.5 MB L3-resident buffer).
//  - fragment-linear LDS layouts for X and W: every MFMA ds_read_b128 is
//    lane-consecutive 16B (conflict-free), addr = frag_base*512 + (l15*4+quad)*8.
//  - LDS 40960 B (X 16 KB unpadded + W 24 KB); 3 blocks/CU; VGPR ~150 < 170 cap.
__global__ __launch_bounds__(256, 3) void qkv_proj(
    const ushort_t* __restrict__ Xb, const ushort_t* __restrict__ Wsz,
    ushort_t* __restrict__ Qb, ushort_t* __restrict__ Kb, ushort_t* __restrict__ Vg)
{
    const int m0 = blockIdx.x * 128;
    const int h  = blockIdx.y;

    __shared__ ushort_t smem[128 * 64 + 3 * 4096];   // 16384 + 24576 B = 40960 B
    ushort_t* Xs  = smem;              // X tile, fragment-linear
    ushort_t* Wts = smem + 128 * 64;   // 3 W panels, fragment-linear
    ushort_t* XsT = smem;              // 64 x 136 overlay, used after K-loop

    const int tid  = threadIdx.x;
    const int w    = tid >> 6;
    const int lane = tid & 63;
    const int quad = lane >> 4;
    const int l15  = lane & 15;
    const int lp8  = (l15 * 4 + quad) * 8;   // lane fragment offset (ushorts)

    fvec4 acc[3][2][4];
    #pragma unroll
    for (int wt = 0; wt < 3; wt++)
        #pragma unroll
        for (int i = 0; i < 2; i++)
            #pragma unroll
            for (int j = 0; j < 4; j++) acc[wt][i][j] = (fvec4){0.f, 0.f, 0.f, 0.f};

    const ushort_t* xsrc = Xb + (size_t)m0 * D_;
    const ushort_t* wsrc = Wsz + (size_t)(h * 12) * 3 * 4096;

    // X staging map: v = tid+256i -> row r = v>>3, chunk t = v&7 (ks=t>>2, q=t&3);
    // LDS u16-unit = ((r>>4)*2 + ks)*64 + (r&15)*4 + q  (fragment-linear)
    int xr[4], xdu[4];
    #pragma unroll
    for (int i = 0; i < 4; i++) {
        int v = tid + 256 * i;
        int r = v >> 3, t = v & 7;
        xr[i]  = r * D_ + t * 8;                                    // global offset (cols later)
        xdu[i] = (((r >> 4) * 2 + (t >> 2)) * 64 + (r & 15) * 4 + (t & 3)) * 8;
    }

    // prologue: X(0) into registers
    svec8 xd[4];
    #pragma unroll
    for (int i = 0; i < 4; i++) xd[i] = *(const svec8*)(xsrc + xr[i]);

    for (int kt = 0; kt < 12; kt++) {
        // W panels for this k-tile (L2-hot linear copy)
        const ushort_t* wp = wsrc + (size_t)kt * 3 * 4096;
        svec8 wd[6];
        #pragma unroll
        for (int j = 0; j < 6; j++)
            wd[j] = *(const svec8*)(wp + (tid + 256 * j) * 8);
        // write staged X + W to LDS
        #pragma unroll
        for (int i = 0; i < 4; i++) *(svec8*)(Xs + xdu[i]) = xd[i];
        #pragma unroll
        for (int j = 0; j < 6; j++) *(svec8*)(Wts + (tid + 256 * j) * 8) = wd[j];
        __syncthreads();

        // prefetch next X tile (in flight across the MFMA phase)
        if (kt < 11) {
            #pragma unroll
            for (int i = 0; i < 4; i++)
                xd[i] = *(const svec8*)(xsrc + xr[i] + (kt + 1) * 64);
        }

        #pragma unroll
        for (int ks = 0; ks < 2; ks++) {
            svec8 a0 = *(const svec8*)(Xs + (4 * w + ks) * 512 + lp8);
            svec8 a1 = *(const svec8*)(Xs + (4 * w + 2 + ks) * 512 + lp8);
            #pragma unroll
            for (int wt = 0; wt < 3; wt++)
                #pragma unroll
                for (int ns = 0; ns < 4; ns++) {
                    svec8 b = *(const svec8*)(Wts + (wt * 8 + ks * 4 + ns) * 512 + lp8);
                    acc[wt][0][ns] = mfma16(a0, b, acc[wt][0][ns]);
                    acc[wt][1][ns] = mfma16(a1, b, acc[wt][1][ns]);
                }
        }
        __syncthreads();
    }

    // epilogue: Q (pre-scaled to log2 domain) and K direct stores
    const float qs = 0.18033688011112042f;   // 1/8 * log2(e)
    #pragma unroll
    for (int ms = 0; ms < 2; ms++)
        #pragma unroll
        for (int ns = 0; ns < 4; ns++)
            #pragma unroll
            for (int r = 0; r < 4; r++) {
                int row = m0 + 32 * w + ms * 16 + quad * 4 + r;
                int col = h * DH_ + ns * 16 + l15;
                Qb[(size_t)row * D_ + col] = bfc(acc[0][ms][ns][r] * qs);
                Kb[(size_t)row * D_ + col] = bfc(acc[1][ms][ns][r]);
            }
    // V: transpose through LDS (whole smem free after the loop's final barrier)
    #pragma unroll
    for (int ms = 0; ms < 2; ms++)
        #pragma unroll
        for (int ns = 0; ns < 4; ns++)
            #pragma unroll
            for (int r = 0; r < 4; r++) {
                int sl = 32 * w + ms * 16 + quad * 4 + r;
                int e  = ns * 16 + l15;
                XsT[e * 136 + sl] = bfc(acc[2][ms][ns][r]);
            }
    __syncthreads();
    #pragma unroll
    for (int i = 0; i < 4; i++) {
        int v = tid + 256 * i;
        int e = v >> 4, s0 = (v & 15) * 8;
        svec8 d = *(const svec8*)(XsT + e * 136 + s0);
        *(svec8*)(Vg + (size_t)(h * DH_ + e) * BS_ + m0 + s0) = d;
    }
}

// ---------------- causal flash attention (R12 kernel, unchanged) ----------------
// Flat de-aliased grid, swapped QK^T, in-register P, spill-free at 48 VGPR,
// skip-rescale + cvt_pk packing. 113 us, MfmaUtil 20 / VALUBusy 66.
__global__ __launch_bounds__(256, 5) void attn(
    const ushort_t* __restrict__ Qb, const ushort_t* __restrict__ Kb,
    const ushort_t* __restrict__ Vg, float* __restrict__ Out)
{
    const int fid = blockIdx.x;                        // 0..1535 flat
    const int qt  = (S_ / 64 - 1) - fid / (H_ * B_);   // long tiles first, de-aliased
    const int r24 = fid % (H_ * B_);
    const int h   = r24 % H_;
    const int b   = r24 / H_;
    const int q0 = qt * 64;

    const int tid  = threadIdx.x;
    const int w    = tid >> 6;
    const int lane = tid & 63;
    const int quad = lane >> 4;
    const int l15  = lane & 15;

    __shared__ ushort_t Ks[64 * 72];       // K tile, ROW-PERMUTED: LDS row m = key pi(m)
    __shared__ ushort_t Vt[64 * 72];       // V^T tile [e][key]

    const size_t hb = (size_t)b * S_ * D_ + (size_t)h * DH_;
    const ushort_t* Vh = Vg + (size_t)h * DH_ * BS_ + (size_t)b * S_;

    const int sr = tid >> 3;          // staging row 0..31 (+32)
    const int sc = (tid & 7) * 8;
    // pinv(k): LDS row where key k lives.  m4=k5, m3=k4, m2=k3, m5=k2, m1m0=k1k0
    const int pr0 = (((sr      >> 2) & 1) << 5) | (((sr      >> 5) & 1) << 4) |
                    (((sr      >> 4) & 1) << 3) | (((sr      >> 3) & 1) << 2) | (sr & 3);
    const int sr1 = sr + 32;
    const int pr1 = (((sr1 >> 2) & 1) << 5) | (((sr1 >> 5) & 1) << 4) |
                    (((sr1 >> 4) & 1) << 3) | (((sr1 >> 3) & 1) << 2) | (sr1 & 3);

    // Q fragments (pre-scaled to log2 domain in qkv_proj); B-operand, same layout
    svec8 aq[2];
    {
        const ushort_t* qrow = Qb + hb + (size_t)(q0 + 16 * w + l15) * D_;
        aq[0] = *(const svec8*)(qrow + quad * 8);
        aq[1] = *(const svec8*)(qrow + 32 + quad * 8);
    }

    float m_i = -INFINITY;
    float ls  = 0.f;                  // per-lane partial denominator (row q = l15)
    fvec4 acc[4];
    #pragma unroll
    for (int n = 0; n < 4; n++) acc[n] = (fvec4){0.f, 0.f, 0.f, 0.f};

    // strength-reduced prefetch pointers (advance per tile)
    const ushort_t* kp = Kb + hb + (size_t)sr * D_ + sc;
    const ushort_t* vp = Vh + (size_t)sr * BS_ + sc;

    // prologue: stage tile 0
    svec8 kd[2], vd[2];
    kd[0] = *(const svec8*)(kp);
    kd[1] = *(const svec8*)(kp + (size_t)32 * D_);
    vd[0] = *(const svec8*)(vp);
    vd[1] = *(const svec8*)(vp + (size_t)32 * BS_);
    kp += (size_t)64 * D_;
    vp += 64;
    *(svec8*)(Ks + pr0 * 72 + sc) = kd[0];
    *(svec8*)(Ks + pr1 * 72 + sc) = kd[1];
    *(svec8*)(Vt + sr  * 72 + sc) = vd[0];
    *(svec8*)(Vt + sr1 * 72 + sc) = vd[1];

    for (int kt = 0; kt <= qt; ++kt) {
        __syncthreads();   // staged tile kt visible to all waves

        // prefetch next tile into registers (in flight across the compute phase)
        if (kt < qt) {
            kd[0] = *(const svec8*)(kp);
            kd[1] = *(const svec8*)(kp + (size_t)32 * D_);
            vd[0] = *(const svec8*)(vp);
            vd[1] = *(const svec8*)(vp + (size_t)32 * BS_);
            kp += (size_t)64 * D_;
            vp += 64;
        }

        // S^T = K_perm Q^T  (log2 domain via pre-scaled Q); lane holds row q = l15
        fvec4 st[4];
        #pragma unroll
        for (int n = 0; n < 4; n++) st[n] = (fvec4){0.f, 0.f, 0.f, 0.f};
        #pragma unroll
        for (int ks = 0; ks < 2; ks++)
            #pragma unroll
            for (int n = 0; n < 4; n++) {
                svec8 ka = *(const svec8*)(Ks + (n * 16 + l15) * 72 + ks * 32 + quad * 8);
                st[n] = mfma16(ka, aq[ks], st[n]);
            }

        // causal mask on the diagonal tile: key pi(m) vs q row
        if (kt == qt) {
            #pragma unroll
            for (int n = 0; n < 4; n++)
                #pragma unroll
                for (int r = 0; r < 4; r++) {
                    int key = (n & 1) * 32 + quad * 8 + (n >> 1) * 4 + r;
                    int row = 16 * w + l15;
                    if (key > row) st[n][r] = -INFINITY;
                }
        }

        // per-row max: two max3-friendly chains, then 2-step butterfly across quads
        float mxa = fmaxf(fmaxf(st[0][0], st[0][1]), st[0][2]);
        mxa = fmaxf(fmaxf(mxa, st[0][3]), st[1][0]);
        mxa = fmaxf(fmaxf(mxa, st[1][1]), st[1][2]);
        mxa = fmaxf(mxa, st[1][3]);
        float mxb = fmaxf(fmaxf(st[2][0], st[2][1]), st[2][2]);
        mxb = fmaxf(fmaxf(mxb, st[2][3]), st[3][0]);
        mxb = fmaxf(fmaxf(mxb, st[3][1]), st[3][2]);
        mxb = fmaxf(mxb, st[3][3]);
        float mx = fmaxf(mxa, mxb);
        mx = fmaxf(mx, __shfl_xor(mx, 16));
        mx = fmaxf(mx, __shfl_xor(mx, 32));

        // skip-rescale: alpha == 1.0 for every row unless some row's max grew.
        if (__any(mx > m_i)) {
            float mn = fmaxf(m_i, mx);
            float alpha = exp2f(m_i - mn);
            m_i = mn;
            ls *= alpha;
            float ar[4];
            #pragma unroll
            for (int r = 0; r < 4; r++)
                ar[r] = __shfl(alpha, quad * 16 + quad * 4 + r);
            #pragma unroll
            for (int n = 0; n < 4; n++)
                #pragma unroll
                for (int r = 0; r < 4; r++) acc[n][r] *= ar[r];
        }

        // p = exp2(st - m_i); pack pairs with v_cvt_pk_bf16_f32; tree-sum denominator
        ivec4 ai0, ai1;
        float psum[4];
        #pragma unroll
        for (int n = 0; n < 4; n++) {
            float p0 = exp2f(st[n][0] - m_i);
            float p1 = exp2f(st[n][1] - m_i);
            float p2 = exp2f(st[n][2] - m_i);
            float p3 = exp2f(st[n][3] - m_i);
            psum[n] = (p0 + p1) + (p2 + p3);
            unsigned d0 = cvt_pk_bf16(p0, p1);
            unsigned d1 = cvt_pk_bf16(p2, p3);
            if (n == 0)      { ai0[0] = (int)d0; ai0[1] = (int)d1; }
            else if (n == 1) { ai1[0] = (int)d0; ai1[1] = (int)d1; }
            else if (n == 2) { ai0[2] = (int)d0; ai0[3] = (int)d1; }
            else             { ai1[2] = (int)d0; ai1[3] = (int)d1; }
        }
        ls += (psum[0] + psum[2]) + (psum[1] + psum[3]);
        svec8 ap0 = __builtin_bit_cast(svec8, ai0);
        svec8 ap1 = __builtin_bit_cast(svec8, ai1);

        // O += P V   (A = in-register P fragment, B = V^T from LDS)
        #pragma unroll
        for (int ks = 0; ks < 2; ks++) {
            svec8 ap = ks ? ap1 : ap0;
            #pragma unroll
            for (int n = 0; n < 4; n++) {
                svec8 bv = *(const svec8*)(Vt + (n * 16 + l15) * 72 + ks * 32 + quad * 8);
                acc[n] = mfma16(ap, bv, acc[n]);
            }
        }

        __syncthreads();   // all waves done reading tile kt

        if (kt < qt) {
            *(svec8*)(Ks + pr0 * 72 + sc) = kd[0];
            *(svec8*)(Ks + pr1 * 72 + sc) = kd[1];
            *(svec8*)(Vt + sr  * 72 + sc) = vd[0];
            *(svec8*)(Vt + sr1 * 72 + sc) = vd[1];
        }
    }

    // epilogue: full denominator for row l15 (2 shuffles), then fetch per-acc-row
    float lsum = ls;
    lsum += __shfl_xor(lsum, 16);
    lsum += __shfl_xor(lsum, 32);
    float li[4];
    #pragma unroll
    for (int r = 0; r < 4; r++)
        li[r] = __shfl(lsum, quad * 16 + quad * 4 + r);
    #pragma unroll
    for (int n = 0; n < 4; n++)
        #pragma unroll
        for (int r = 0; r < 4; r++) {
            int row = q0 + 16 * w + quad * 4 + r;
            int col = h * DH_ + n * 16 + l15;
            Out[((size_t)b * S_ + row) * D_ + col] = acc[n][r] / li[r];
        }
}

extern "C" void kernel_launch(void* const* d_in, const int* in_sizes, int n_in,
                              void* d_out, int out_size, void* d_ws, size_t ws_size,
                              hipStream_t stream)
{
    const float* X  = (const float*)d_in[0];
    const float* Wq = (const float*)d_in[1];
    const float* Wk = (const float*)d_in[2];
    const float* Wv = (const float*)d_in[3];

    ushort_t* Qb = (ushort_t*)d_ws;                      // 8192*768 bf16 (pre-scaled)
    ushort_t* Kb = Qb + (size_t)BS_ * D_;                // 8192*768 bf16
    ushort_t* Vg = Kb + (size_t)BS_ * D_;                // [768][8192] bf16 transposed

    // scratch inside d_out (25.2 MB fp32 buffer): attn fully overwrites it at the
    // end, and prep/qkv/attn serialize on one stream -> safe.
    ushort_t* Xb  = (ushort_t*)d_out;                    // [8192][768] bf16 (12.6 MB)
    ushort_t* Wsz = Xb + (size_t)BS_ * D_;               // [h][kt][wt][4096] (3.5 MB)
    float* Out = (float*)d_out;

    prep<<<dim3(3072 + 432), dim3(256), 0, stream>>>(X, Wq, Wk, Wv, Xb, Wsz);
    qkv_proj<<<dim3(64, H_), dim3(256), 0, stream>>>(Xb, Wsz, Qb, Kb, Vg);
    attn<<<dim3((S_ / 64) * H_ * B_), dim3(256), 0, stream>>>(Qb, Kb, Vg, Out);
}